// Round 1
// baseline (185.229 us; speedup 1.0000x reference)
//
#include <hip/hip_runtime.h>

#define SEQ 1024
#define DK 8
#define NH 12
#define BATCH 8
#define NQ 96
#define ED 768

// ---------------------------------------------------------------------------
// Kernel 1: fused q-compute + attention for one (b, h, 256-row chunk).
// q tile (1024x8 fp32 = 32 KB) lives in LDS; each thread owns one query row,
// loops over all 1024 keys (broadcast LDS reads), online-accumulates
// sum(exp) and sum(exp * q_t).  No max-subtraction needed: |score| <= 2.83.
// ---------------------------------------------------------------------------
__global__ __launch_bounds__(256) void attn_kernel(
    const float* __restrict__ x, const float* __restrict__ theta,
    float* __restrict__ attn /* (BATCH*SEQ, NQ) row-major */)
{
    __shared__ __align__(16) float qs[SEQ * DK];  // 32 KB

    const int rc  = blockIdx.x;   // row chunk 0..3
    const int h   = blockIdx.y;   // head 0..11
    const int b   = blockIdx.z;   // batch 0..7
    const int tid = threadIdx.x;

    // Each thread's float4-column within a row is fixed: cl = (tid&1)*4.
    const int cl = (tid & 1) * 4;
    float ct0 = __cosf(theta[h * DK + cl + 0]);
    float ct1 = __cosf(theta[h * DK + cl + 1]);
    float ct2 = __cosf(theta[h * DK + cl + 2]);
    float ct3 = __cosf(theta[h * DK + cl + 3]);

    // Stage q into LDS: 2048 float4s, 8 per thread.
    #pragma unroll
    for (int k = 0; k < 8; ++k) {
        const int f = tid + 256 * k;     // float4 index
        const int s = f >> 1;            // row 0..1023
        const float4 v = *(const float4*)(x + ((size_t)(b * SEQ + s)) * ED + h * DK + cl);
        qs[s * DK + cl + 0] = __cosf(v.x) * ct0;
        qs[s * DK + cl + 1] = __cosf(v.y) * ct1;
        qs[s * DK + cl + 2] = __cosf(v.z) * ct2;
        qs[s * DK + cl + 3] = __cosf(v.w) * ct3;
    }
    __syncthreads();

    // My query row.
    const int i = rc * 256 + tid;
    const float4 qi0 = *(const float4*)&qs[i * DK + 0];
    const float4 qi1 = *(const float4*)&qs[i * DK + 4];

    float acc0 = 0.f, acc1 = 0.f, acc2 = 0.f, acc3 = 0.f;
    float acc4 = 0.f, acc5 = 0.f, acc6 = 0.f, acc7 = 0.f;
    float l = 0.f;

    const float scale = 0.35355339059327373f;  // 1/sqrt(8)

    #pragma unroll 4
    for (int t = 0; t < SEQ; ++t) {
        const float4 a = *(const float4*)&qs[t * DK + 0];
        const float4 c = *(const float4*)&qs[t * DK + 4];
        float dot = qi0.x * a.x + qi0.y * a.y + qi0.z * a.z + qi0.w * a.w
                  + qi1.x * c.x + qi1.y * c.y + qi1.z * c.z + qi1.w * c.w;
        const float p = __expf(dot * scale);
        l += p;
        acc0 += p * a.x; acc1 += p * a.y; acc2 += p * a.z; acc3 += p * a.w;
        acc4 += p * c.x; acc5 += p * c.y; acc6 += p * c.z; acc7 += p * c.w;
    }

    const float inv = 1.0f / l;
    float* o = attn + ((size_t)(b * SEQ + i)) * NQ + h * DK;
    float4 o0 = make_float4(acc0 * inv, acc1 * inv, acc2 * inv, acc3 * inv);
    float4 o1 = make_float4(acc4 * inv, acc5 * inv, acc6 * inv, acc7 * inv);
    *(float4*)(o + 0) = o0;
    *(float4*)(o + 4) = o1;
}

// ---------------------------------------------------------------------------
// Kernel 2: out = attn @ W^T.  M=8192, N=768, K=96, fp32.
// 64x64 tile per 256-thread block, 4x4 micro-tile, LDS stride padded to 100.
// ---------------------------------------------------------------------------
__global__ __launch_bounds__(256) void proj_kernel(
    const float* __restrict__ attn, const float* __restrict__ W,
    float* __restrict__ out)
{
    __shared__ __align__(16) float As[64][100];
    __shared__ __align__(16) float Bs[64][100];

    const int bx  = blockIdx.x;   // N tile 0..11
    const int by  = blockIdx.y;   // M tile 0..127
    const int tid = threadIdx.x;
    const int tx  = tid & 15;
    const int ty  = tid >> 4;

    // Stage: 64 rows x 96 cols = 1536 float4s each, 6 per thread.
    #pragma unroll
    for (int k = 0; k < 6; ++k) {
        const int f = tid + 256 * k;
        const int r = f / 24;
        const int c = (f % 24) * 4;
        const float4 va = *(const float4*)(attn + ((size_t)(by * 64 + r)) * NQ + c);
        *(float4*)&As[r][c] = va;
        const float4 vb = *(const float4*)(W + ((size_t)(bx * 64 + r)) * NQ + c);
        *(float4*)&Bs[r][c] = vb;
    }
    __syncthreads();

    float acc[4][4] = {};
    #pragma unroll 6
    for (int k = 0; k < NQ; k += 4) {
        float4 a[4], bv[4];
        #pragma unroll
        for (int i = 0; i < 4; ++i) a[i]  = *(const float4*)&As[ty * 4 + i][k];
        #pragma unroll
        for (int j = 0; j < 4; ++j) bv[j] = *(const float4*)&Bs[tx * 4 + j][k];
        #pragma unroll
        for (int i = 0; i < 4; ++i)
            #pragma unroll
            for (int j = 0; j < 4; ++j)
                acc[i][j] += a[i].x * bv[j].x + a[i].y * bv[j].y
                           + a[i].z * bv[j].z + a[i].w * bv[j].w;
    }

    #pragma unroll
    for (int i = 0; i < 4; ++i) {
        float4 v = make_float4(acc[i][0], acc[i][1], acc[i][2], acc[i][3]);
        *(float4*)(out + ((size_t)(by * 64 + ty * 4 + i)) * ED + bx * 64 + tx * 4) = v;
    }
}

extern "C" void kernel_launch(void* const* d_in, const int* in_sizes, int n_in,
                              void* d_out, int out_size, void* d_ws, size_t ws_size,
                              hipStream_t stream) {
    const float* x     = (const float*)d_in[0];
    const float* theta = (const float*)d_in[1];
    const float* W     = (const float*)d_in[2];
    float* out  = (float*)d_out;
    float* attn = (float*)d_ws;   // 8192 x 96 fp32 = 3 MB

    attn_kernel<<<dim3(4, NH, BATCH), 256, 0, stream>>>(x, theta, attn);
    proj_kernel<<<dim3(ED / 64, (BATCH * SEQ) / 64), 256, 0, stream>>>(attn, W, out);
}

// Round 2
// 135.096 us; speedup vs baseline: 1.3711x; 1.3711x over previous
//
#include <hip/hip_runtime.h>
#include <hip/hip_bf16.h>

#define SEQ 1024
#define DK 8
#define NH 12
#define BATCH 8
#define NQ 96
#define ED 768

typedef __attribute__((ext_vector_type(8))) short short8;
typedef __attribute__((ext_vector_type(4))) float floatx4;

__device__ __forceinline__ float fast_exp2(float x) {
#if __has_builtin(__builtin_amdgcn_exp2f)
    return __builtin_amdgcn_exp2f(x);
#else
    return exp2f(x);
#endif
}

// ---------------------------------------------------------------------------
// Kernel 1: fused q-compute + attention.
// Block = 256 threads handles (b, h, 128-query chunk).  q tile (1024x8 fp32 =
// 32 KB) in LDS.  Each thread: 4 queries x 128 keys (8-way key split across
// lanes, g = tid&7).  Keys interleaved t = i*8+g so the 8 distinct LDS
// addresses per wave hit 4 bank-groups (2-way aliasing = free).  No softmax
// max-subtraction needed (|score| <= 2.83); partial sums combine additively
// via 3 shfl_xor levels.  Output written bf16 for the MFMA projection.
// ---------------------------------------------------------------------------
__global__ __launch_bounds__(256) void attn_kernel(
    const float* __restrict__ x, const float* __restrict__ theta,
    __hip_bfloat16* __restrict__ attn /* (BATCH*SEQ, NQ) bf16 row-major */)
{
    __shared__ __align__(16) float qs[SEQ * DK];  // 32 KB

    const int qc  = blockIdx.x;   // query chunk 0..7 (128 queries each)
    const int h   = blockIdx.y;
    const int b   = blockIdx.z;
    const int tid = threadIdx.x;

    // Stage q = cos(x)*cos(theta) into LDS.  Each thread: fixed half-row.
    const int cl = (tid & 1) * 4;
    const float ct0 = __cosf(theta[h * DK + cl + 0]);
    const float ct1 = __cosf(theta[h * DK + cl + 1]);
    const float ct2 = __cosf(theta[h * DK + cl + 2]);
    const float ct3 = __cosf(theta[h * DK + cl + 3]);

    #pragma unroll
    for (int k = 0; k < 8; ++k) {
        const int f = tid + 256 * k;     // float4 index 0..2047
        const int s = f >> 1;            // row 0..1023
        const float4 v = *(const float4*)(x + ((size_t)(b * SEQ + s)) * ED + h * DK + cl);
        float4 qv;
        qv.x = __cosf(v.x) * ct0;
        qv.y = __cosf(v.y) * ct1;
        qv.z = __cosf(v.z) * ct2;
        qv.w = __cosf(v.w) * ct3;
        *(float4*)&qs[s * DK + cl] = qv;
    }
    __syncthreads();

    const int g  = tid & 7;    // key-split lane group
    const int qg = tid >> 3;   // 0..31
    const int q0 = qc * 128 + qg * 4;

    // 4 query rows, pre-scaled by (1/sqrt(8)) * log2(e) so p = exp2(dot).
    const float kscale = 0.35355339059327373f * 1.4426950408889634f;
    float qi[4][8];
    #pragma unroll
    for (int j = 0; j < 4; ++j)
        #pragma unroll
        for (int k = 0; k < 8; ++k)
            qi[j][k] = qs[(q0 + j) * DK + k] * kscale;

    float l[4] = {0.f, 0.f, 0.f, 0.f};
    float acc[4][8] = {};

    const float* p = qs + g * DK;   // key t = i*8 + g
    #pragma unroll 2
    for (int i = 0; i < 128; ++i) {
        const floatx4 a0 = *(const floatx4*)(p);
        const floatx4 a1 = *(const floatx4*)(p + 4);
        p += 8 * DK;
        float ae[8] = {a0.x, a0.y, a0.z, a0.w, a1.x, a1.y, a1.z, a1.w};
        #pragma unroll
        for (int j = 0; j < 4; ++j) {
            // balanced dot tree (4 independent chains across j)
            float e0 = qi[j][0] * ae[0] + qi[j][1] * ae[1];
            float e1 = qi[j][2] * ae[2] + qi[j][3] * ae[3];
            float e2 = qi[j][4] * ae[4] + qi[j][5] * ae[5];
            float e3 = qi[j][6] * ae[6] + qi[j][7] * ae[7];
            float pj = fast_exp2((e0 + e1) + (e2 + e3));
            l[j] += pj;
            #pragma unroll
            for (int k = 0; k < 8; ++k)
                acc[j][k] += pj * ae[k];
        }
    }

    // Combine the 8 key-split partials (lanes differing in bits 0..2).
    #pragma unroll
    for (int j = 0; j < 4; ++j) {
        l[j] += __shfl_xor(l[j], 1);
        l[j] += __shfl_xor(l[j], 2);
        l[j] += __shfl_xor(l[j], 4);
        #pragma unroll
        for (int k = 0; k < 8; ++k) {
            acc[j][k] += __shfl_xor(acc[j][k], 1);
            acc[j][k] += __shfl_xor(acc[j][k], 2);
            acc[j][k] += __shfl_xor(acc[j][k], 4);
        }
    }

    if (g == 0) {
        #pragma unroll
        for (int j = 0; j < 4; ++j) {
            const float inv = 1.0f / l[j];
            union { short8 v; __hip_bfloat16 hh[8]; } o;
            #pragma unroll
            for (int k = 0; k < 8; ++k)
                o.hh[k] = __float2bfloat16(acc[j][k] * inv);
            *(short8*)(attn + ((size_t)(b * SEQ + q0 + j)) * NQ + h * DK) = o.v;
        }
    }
}

// ---------------------------------------------------------------------------
// Kernel 2: W (768x96 fp32) -> bf16.
// ---------------------------------------------------------------------------
__global__ __launch_bounds__(256) void wconv_kernel(
    const float* __restrict__ W, __hip_bfloat16* __restrict__ Wb)
{
    const int i = blockIdx.x * 256 + threadIdx.x;   // float4 index, 18432 total
    const float4 v = ((const float4*)W)[i];
    union { ushort4 u; __hip_bfloat16 hh[4]; } o;
    o.hh[0] = __float2bfloat16(v.x);
    o.hh[1] = __float2bfloat16(v.y);
    o.hh[2] = __float2bfloat16(v.z);
    o.hh[3] = __float2bfloat16(v.w);
    ((ushort4*)Wb)[i] = o.u;
}

// ---------------------------------------------------------------------------
// Kernel 3: out = attn_bf16 @ Wb^T via 16x16x32 bf16 MFMA, fp32 accumulate.
// M=8192, N=768, K=96.  No LDS: attn (1.5 MB) and W (147 KB) are L2-resident.
// Block 256 = 4 waves; each wave does a 16(M) x 64(N) patch = 4 col-tiles
// x 3 k-steps = 12 MFMAs.
// A frag:  lane holds A[m = lane&15][k = (lane>>4)*8 + j]  (contiguous 16 B)
// B frag:  lane holds B[k = (lane>>4)*8 + j][n = lane&15] = W[n][k] (contig)
// D frag:  D[row = (lane>>4)*4 + r][col = lane&15]
// ---------------------------------------------------------------------------
__global__ __launch_bounds__(256) void proj_kernel(
    const __hip_bfloat16* __restrict__ attn, const __hip_bfloat16* __restrict__ Wb,
    float* __restrict__ out)
{
    const int tid  = threadIdx.x;
    const int w    = tid >> 6;       // wave 0..3
    const int lane = tid & 63;
    const int l15  = lane & 15;
    const int quad = lane >> 4;      // 0..3

    const int m0 = blockIdx.y * 64 + w * 16;
    const int n0 = blockIdx.x * 64;

    const size_t abase = ((size_t)(m0 + l15)) * NQ + quad * 8;
    short8 af0 = *(const short8*)(attn + abase);
    short8 af1 = *(const short8*)(attn + abase + 32);
    short8 af2 = *(const short8*)(attn + abase + 64);

    floatx4 acc[4];
    #pragma unroll
    for (int c = 0; c < 4; ++c) acc[c] = (floatx4){0.f, 0.f, 0.f, 0.f};

    #pragma unroll
    for (int c = 0; c < 4; ++c) {
        const size_t bbase = ((size_t)(n0 + c * 16 + l15)) * NQ + quad * 8;
        short8 b0 = *(const short8*)(Wb + bbase);
        short8 b1 = *(const short8*)(Wb + bbase + 32);
        short8 b2 = *(const short8*)(Wb + bbase + 64);
        acc[c] = __builtin_amdgcn_mfma_f32_16x16x32_bf16(af0, b0, acc[c], 0, 0, 0);
        acc[c] = __builtin_amdgcn_mfma_f32_16x16x32_bf16(af1, b1, acc[c], 0, 0, 0);
        acc[c] = __builtin_amdgcn_mfma_f32_16x16x32_bf16(af2, b2, acc[c], 0, 0, 0);
    }

    #pragma unroll
    for (int c = 0; c < 4; ++c)
        #pragma unroll
        for (int r = 0; r < 4; ++r)
            out[((size_t)(m0 + quad * 4 + r)) * ED + n0 + c * 16 + l15] = acc[c][r];
}

extern "C" void kernel_launch(void* const* d_in, const int* in_sizes, int n_in,
                              void* d_out, int out_size, void* d_ws, size_t ws_size,
                              hipStream_t stream) {
    const float* x     = (const float*)d_in[0];
    const float* theta = (const float*)d_in[1];
    const float* W     = (const float*)d_in[2];
    float* out = (float*)d_out;

    __hip_bfloat16* attn = (__hip_bfloat16*)d_ws;                         // 1.5 MB
    __hip_bfloat16* Wb   = (__hip_bfloat16*)((char*)d_ws + (size_t)BATCH * SEQ * NQ * 2);

    wconv_kernel<<<dim3(ED * NQ / 4 / 256), 256, 0, stream>>>(W, Wb);
    attn_kernel<<<dim3(8, NH, BATCH), 256, 0, stream>>>(x, theta, attn);
    proj_kernel<<<dim3(ED / 64, (BATCH * SEQ) / 64), 256, 0, stream>>>(attn, Wb, out);
}

// Round 7
// 120.297 us; speedup vs baseline: 1.5398x; 1.1230x over previous
//
#include <hip/hip_runtime.h>
#include <hip/hip_bf16.h>

#define SEQ 1024
#define DK 8
#define NH 12
#define BATCH 8
#define NQ 96
#define ED 768

typedef __attribute__((ext_vector_type(8))) _Float16 half8;
typedef __attribute__((ext_vector_type(2))) __fp16 fp16x2;
typedef __attribute__((ext_vector_type(4))) float floatx4;
typedef __attribute__((ext_vector_type(2))) unsigned uint2v;

__device__ __forceinline__ float fast_exp2(float x) {
#if __has_builtin(__builtin_amdgcn_exp2f)
    return __builtin_amdgcn_exp2f(x);
#else
    return exp2f(x);
#endif
}

// Pack two fp32 -> fp16x2 in one v_cvt_pkrtz_f16_f32, as a 32-bit word.
__device__ __forceinline__ unsigned pkh(float lo, float hi) {
    union { fp16x2 h; unsigned u; } v;
    v.h = __builtin_amdgcn_cvt_pkrtz(lo, hi);
    return v.u;
}

// ---------------------------------------------------------------------------
// Fused quantum-attention via fp16 MFMA.  One block = (b, h, 128-query
// chunk), 512 threads = 8 waves; each wave owns 16 query rows, loops over
// 1024 keys in 32-key windows.  Scores bounded (|exp2-arg| <= 4.08) => no
// online-softmax max/rescale.
//
// R6 change (the fix): the P matrix (exp2 of scores) is round-tripped
// through LDS between the QK^T and PV MFMAs — the m120-verified transform —
// instead of the in-register shfl transpose (R2–R5's structural-error
// suspect).  Score D-values are written at explicit (query,key) addresses
// (P^T tile, stride 36 halfs: b64/b128-aligned, uniform 2-way banks) and
// the PV A-frag is read back by address, so the key/query mapping is
// correct by construction.  Softmax denominator: fp32 lacc over the same
// e-values, quad-reduced via shfl_xor(16,32) -> L[query l15] in every lane.
//
// LDS:
//   qv  (1024x8 fp16, scaled by sqrt(log2e/sqrt8)) — feeds A and B of QK^T.
//   qvt (tiled V'): (win,q,n,j) -> win*512 + q*128 + n*8 + j; PV B-frag is
//        one contiguous ds_read_b128 per lane (cols 8..15 zero).
//   pt  per-wave P^T tile: addr = query*36 + key  (query 0..15, key 0..31).
// ---------------------------------------------------------------------------
__global__ __launch_bounds__(512) void attn_kernel(
    const float* __restrict__ x, const float* __restrict__ theta,
    _Float16* __restrict__ attn /* (BATCH*SEQ, NQ) fp16 */)
{
    __shared__ __align__(16) _Float16 qv[SEQ * DK];    // 16 KB
    __shared__ __align__(16) _Float16 qvt[32 * 512];   // 32 KB
    __shared__ __align__(16) _Float16 pt[8 * 576];     // 9 KB (1152 B / wave)

    const int chunk = blockIdx.x;   // 0..7  (128 queries)
    const int h     = blockIdx.y;
    const int b     = blockIdx.z;
    const int tid   = threadIdx.x;

    const float SQS = 0.71419170f;  // sqrt(log2(e)/sqrt(8))

    float ct[8];
    #pragma unroll
    for (int k = 0; k < 8; ++k) ct[k] = __cosf(theta[h * DK + k]);

    // ---- stage q into qv (scaled) and qvt (tiled, unscaled) ----
    #pragma unroll
    for (int it = 0; it < 2; ++it) {
        const int s = tid + it * 512;
        const float* xp = x + ((size_t)(b * SEQ + s)) * ED + h * DK;
        const float4 v0 = *(const float4*)xp;
        const float4 v1 = *(const float4*)(xp + 4);
        float q[8];
        q[0] = __cosf(v0.x) * ct[0]; q[1] = __cosf(v0.y) * ct[1];
        q[2] = __cosf(v0.z) * ct[2]; q[3] = __cosf(v0.w) * ct[3];
        q[4] = __cosf(v1.x) * ct[4]; q[5] = __cosf(v1.y) * ct[5];
        q[6] = __cosf(v1.z) * ct[6]; q[7] = __cosf(v1.w) * ct[7];
        union { half8 v; _Float16 e[8]; } row;
        #pragma unroll
        for (int k = 0; k < 8; ++k) row.e[k] = (_Float16)(q[k] * SQS);
        *(half8*)&qv[s * DK] = row.v;
        const int e0 = (s >> 5) * 512 + ((s >> 3) & 3) * 128 + (s & 7);
        #pragma unroll
        for (int k = 0; k < 8; ++k) qvt[e0 + k * 8] = (_Float16)q[k];
    }
    // ---- V' columns 8..15: zeros (B-frag lanes 8..15 read them) ----
    {
        const int ww = tid >> 4, qq = (tid >> 2) & 3, np = tid & 3;
        const int n0 = 8 + np * 2;
        const int e  = ww * 512 + qq * 128 + n0 * 8;
        #pragma unroll
        for (int j = 0; j < 8; ++j) { qvt[e + j] = (_Float16)0.0f; qvt[e + 8 + j] = (_Float16)0.0f; }
    }
    __syncthreads();

    const int w    = tid >> 6;       // wave 0..7
    const int lane = tid & 63;
    const int l15  = lane & 15;
    const int qt   = lane >> 4;
    const int m0w  = chunk * 128 + w * 16;

    _Float16* zp = &qvt[72];         // 16 zero bytes (win0,q0,n=9), 16B-aligned
    _Float16* myp = &pt[w * 576];    // this wave's P^T tile

    // Score MFMA B-frag: Q rows of my 16-query tile (quad 0 only; k>=8 zero).
    const half8 bfm = *(const half8*)((qt == 0) ? &qv[(m0w + l15) * DK] : zp);

    const _Float16* pa0 = (qt == 0) ? &qv[l15 * DK]        : zp;
    const _Float16* pa1 = (qt == 0) ? &qv[(16 + l15) * DK] : zp;
    const int ainc = (qt == 0) ? 32 * DK : 0;        // 32 key-rows per window
    const _Float16* pv = &qvt[qt * 128 + l15 * 8];

    // P^T addresses: this lane's d-values are scores(key = 16*half + qt*4+r,
    // query = l15)  [pinned by the R2-passing proj composite].
    _Float16* pw0 = &myp[l15 * 36 + qt * 4];         // keys qt*4 + 0..3
    _Float16* pw1 = pw0 + 16;                        // keys 16 + qt*4 + 0..3
    const _Float16* pr = &myp[l15 * 36 + qt * 8];    // A-frag: keys qt*8 + 0..7 at query l15

    floatx4 acc = {0.f, 0.f, 0.f, 0.f};
    float lacc = 0.f;                 // fp32 softmax denominator partial
    const floatx4 zc = {0.f, 0.f, 0.f, 0.f};

    #pragma unroll 2
    for (int win = 0; win < 32; ++win) {
        const half8 af0 = *(const half8*)pa0;  pa0 += ainc;
        const half8 af1 = *(const half8*)pa1;  pa1 += ainc;
        floatx4 d0 = __builtin_amdgcn_mfma_f32_16x16x32_f16(af0, bfm, zc, 0, 0, 0);
        floatx4 d1 = __builtin_amdgcn_mfma_f32_16x16x32_f16(af1, bfm, zc, 0, 0, 0);

        const float e00 = fast_exp2(d0[0]), e01 = fast_exp2(d0[1]);
        const float e02 = fast_exp2(d0[2]), e03 = fast_exp2(d0[3]);
        const float e10 = fast_exp2(d1[0]), e11 = fast_exp2(d1[1]);
        const float e12 = fast_exp2(d1[2]), e13 = fast_exp2(d1[3]);
        lacc += ((e00 + e01) + (e02 + e03)) + ((e10 + e11) + (e12 + e13));

        // P^T -> LDS at explicit (query,key) addresses.
        *(uint2v*)pw0 = (uint2v){pkh(e00, e01), pkh(e02, e03)};
        *(uint2v*)pw1 = (uint2v){pkh(e10, e11), pkh(e12, e13)};

        // Read back in A-layout; compiler inserts the lgkmcnt dependency wait.
        const half8 paf = *(const half8*)pr;
        const half8 vf  = *(const half8*)pv;  pv += 512;
        acc = __builtin_amdgcn_mfma_f32_16x16x32_f16(paf, vf, acc, 0, 0, 0);
    }

    // Quad-reduce the denominator: L[query l15] in every lane.
    lacc += __shfl_xor(lacc, 16);
    lacc += __shfl_xor(lacc, 32);

    // Row m = qt*4+r is query m0w+qt*4+r; L[m] sits at lanes with l15 = m.
    #pragma unroll
    for (int r = 0; r < 4; ++r) {
        const float lsum = __shfl(lacc, qt * 4 + r);
        const float val  = acc[r] * __builtin_amdgcn_rcpf(lsum);
        if (l15 < 8) {
            const int m = m0w + qt * 4 + r;
            attn[((size_t)(b * SEQ + m)) * NQ + h * DK + l15] = (_Float16)val;
        }
    }
}

// ---------------------------------------------------------------------------
// W (768x96 fp32) -> fp16.
// ---------------------------------------------------------------------------
__global__ __launch_bounds__(256) void wconv_kernel(
    const float* __restrict__ W, _Float16* __restrict__ Wh)
{
    const int i = blockIdx.x * 256 + threadIdx.x;   // float4 index
    const float4 v = ((const float4*)W)[i];
    union { unsigned u[2]; double d; } o;
    o.u[0] = pkh(v.x, v.y);
    o.u[1] = pkh(v.z, v.w);
    ((double*)Wh)[i] = o.d;
}

// ---------------------------------------------------------------------------
// out = attn_fp16 @ Wh^T via 16x16x32 fp16 MFMA (structure verified in R2).
// ---------------------------------------------------------------------------
__global__ __launch_bounds__(256) void proj_kernel(
    const _Float16* __restrict__ attn, const _Float16* __restrict__ Wh,
    float* __restrict__ out)
{
    const int tid  = threadIdx.x;
    const int w    = tid >> 6;
    const int lane = tid & 63;
    const int l15  = lane & 15;
    const int quad = lane >> 4;

    const int m0 = blockIdx.y * 64 + w * 16;
    const int n0 = blockIdx.x * 64;

    const size_t abase = ((size_t)(m0 + l15)) * NQ + quad * 8;
    half8 af0 = *(const half8*)(attn + abase);
    half8 af1 = *(const half8*)(attn + abase + 32);
    half8 af2 = *(const half8*)(attn + abase + 64);

    floatx4 acc[4];
    #pragma unroll
    for (int c = 0; c < 4; ++c) acc[c] = (floatx4){0.f, 0.f, 0.f, 0.f};

    #pragma unroll
    for (int c = 0; c < 4; ++c) {
        const size_t bbase = ((size_t)(n0 + c * 16 + l15)) * NQ + quad * 8;
        half8 b0 = *(const half8*)(Wh + bbase);
        half8 b1 = *(const half8*)(Wh + bbase + 32);
        half8 b2 = *(const half8*)(Wh + bbase + 64);
        acc[c] = __builtin_amdgcn_mfma_f32_16x16x32_f16(af0, b0, acc[c], 0, 0, 0);
        acc[c] = __builtin_amdgcn_mfma_f32_16x16x32_f16(af1, b1, acc[c], 0, 0, 0);
        acc[c] = __builtin_amdgcn_mfma_f32_16x16x32_f16(af2, b2, acc[c], 0, 0, 0);
    }

    #pragma unroll
    for (int c = 0; c < 4; ++c)
        #pragma unroll
        for (int r = 0; r < 4; ++r)
            out[((size_t)(m0 + quad * 4 + r)) * ED + n0 + c * 16 + l15] = acc[c][r];
}

extern "C" void kernel_launch(void* const* d_in, const int* in_sizes, int n_in,
                              void* d_out, int out_size, void* d_ws, size_t ws_size,
                              hipStream_t stream) {
    const float* x     = (const float*)d_in[0];
    const float* theta = (const float*)d_in[1];
    const float* W     = (const float*)d_in[2];
    float* out = (float*)d_out;

    _Float16* attn = (_Float16*)d_ws;                                        // 1.5 MB
    _Float16* Wh   = (_Float16*)((char*)d_ws + (size_t)BATCH * SEQ * NQ * 2);

    wconv_kernel<<<dim3(ED * NQ / 4 / 256), 256, 0, stream>>>(W, Wh);
    attn_kernel<<<dim3(8, NH, BATCH), 512, 0, stream>>>(x, theta, attn);
    proj_kernel<<<dim3(ED / 64, (BATCH * SEQ) / 64), 256, 0, stream>>>(attn, Wh, out);
}